// Round 12
// baseline (779.961 us; speedup 1.0000x reference)
//
#include <hip/hip_runtime.h>
#include <hip/hip_bf16.h>

#define TSTEPS 20
#define SMEM_BYTES 131072

typedef __bf16 bf16x8 __attribute__((ext_vector_type(8)));
typedef float f32x4 __attribute__((ext_vector_type(4)));
typedef unsigned short u16;

__device__ __forceinline__ u16 f2bf(float f) {
  unsigned u = __builtin_bit_cast(unsigned, f);
  u = (u + 0x7FFFu + ((u >> 16) & 1u)) >> 16;  // RNE
  return (u16)u;
}
__device__ __forceinline__ float rcp_(float v) { return __builtin_amdgcn_rcpf(v); }
__device__ __forceinline__ float sig_(float v) { return rcp_(1.f + __expf(-v)); }
__device__ __forceinline__ float tanh_(float v) { return 1.f - 2.f * rcp_(1.f + __expf(2.f * v)); }

#define MFMA16(a, b, c) __builtin_amdgcn_mfma_f32_16x16x32_bf16((a), (b), (c), 0, 0, 0)
#define BAR() asm volatile("s_barrier" ::: "memory")
#define WAITV(n) asm volatile("s_waitcnt vmcnt(" #n ")" ::: "memory")
#define WAITLG() asm volatile("s_waitcnt lgkmcnt(0)" ::: "memory")

__device__ __forceinline__ void gload16(const u16* g, u16* lds) {
#if defined(__HIP_DEVICE_COMPILE__)
  __builtin_amdgcn_global_load_lds(
      (const __attribute__((address_space(1))) unsigned*)g,
      (__attribute__((address_space(3))) unsigned*)lds, 16, 0, 0);
#endif
}

// ---------------- prep kernels ----------------
// permuted Whh: p = s*256 + w*64 + f*16 + j  <-  orig row f*512 + s*64 + w*16 + j
__global__ void convert_whh_p(const float* __restrict__ w, u16* __restrict__ d) {
  int p = blockIdx.x;         // 2048 rows
  int k = threadIdx.x;        // 512 cols
  int j = p & 15, f = (p >> 4) & 3, wg = (p >> 6) & 3, s = p >> 8;
  int orig = (f << 9) + (s << 6) + (wg << 4) + j;
  d[p * 512 + k] = f2bf(w[orig * 512 + k]);
}

// fc1w -> frag-major: idx = (((((s*20+tf)*32+kk2)*2+Fwn)*2+jf)*4+kg)*16+jl, 8 elems.
// value = fc1w[s*64+Fwn*32+jf*16+jl][(k>>9)*10240 + tf*512 + (k&511)], k = kk2*32+kg*8+e
__global__ void fc1p_prep(const float* __restrict__ w, u16* __restrict__ d) {
  int id = blockIdx.x * blockDim.x + threadIdx.x;  // 1310720
  int jl = id & 15, t1 = id >> 4;
  int kg = t1 & 3, t2 = t1 >> 2;
  int jf = t2 & 1, t3 = t2 >> 1;
  int Fwn = t3 & 1, t4 = t3 >> 1;
  int kk2 = t4 & 31, t5 = t4 >> 5;
  int tf = t5 % 20, s = t5 / 20;
  int j = s * 64 + Fwn * 32 + jf * 16 + jl;
  int k = kk2 * 32 + kg * 8;
  const float* src = w + j * 20480 + (k >> 9) * 10240 + tf * 512 + (k & 511);
  float4 v0 = *reinterpret_cast<const float4*>(src);
  float4 v1 = *reinterpret_cast<const float4*>(src + 4);
  u16* dst = d + id * 8;
  dst[0] = f2bf(v0.x); dst[1] = f2bf(v0.y); dst[2] = f2bf(v0.z); dst[3] = f2bf(v0.w);
  dst[4] = f2bf(v1.x); dst[5] = f2bf(v1.y); dst[6] = f2bf(v1.z); dst[7] = f2bf(v1.w);
}

// augmented-B: Bx[p][0..31] = [Wih[o][0], Wih[o][1], bih[o]+bhh[o], 0...]
__global__ void bx_prep(const float* __restrict__ Wih, const float* __restrict__ bih,
                        const float* __restrict__ bhh, u16* __restrict__ Bx) {
  int p = blockIdx.x * blockDim.x + threadIdx.x;
  if (p >= 2048) return;
  int j = p & 15, f = (p >> 4) & 3, wg = (p >> 6) & 3, s = p >> 8;
  int o = (f << 9) + (s << 6) + (wg << 4) + j;
  u16* row = Bx + p * 32;
  row[0] = f2bf(Wih[o * 2 + 0]);
  row[1] = f2bf(Wih[o * 2 + 1]);
  row[2] = f2bf(bih[o] + bhh[o]);
#pragma unroll
  for (int k = 3; k < 32; ++k) row[k] = 0;
}

// h -> bf16; c0 -> per-thread-linear layout matching step256's epilogue; facc -> 0
__global__ void init_state(const float* __restrict__ h0, const float* __restrict__ c0,
                           u16* __restrict__ hbf, float* __restrict__ cws,
                           float* __restrict__ facc, int nh, int nacc) {
  int i = blockIdx.x * blockDim.x + threadIdx.x;
  if (i < nh) {
    hbf[i] = f2bf(h0[i]);
    int r = i & 3, mt = (i >> 2) & 7, lane = (i >> 5) & 63, wid = (i >> 11) & 7, bid = i >> 14;
    int s = (bid >> 3) & 7, nb = (bid & 7) * 4 + (bid >> 6);
    int wm = wid >> 2, wn = wid & 3;
    int jl = lane & 15, kg = lane >> 4;
    int n = nb * 256 + wm * 128 + mt * 16 + kg * 4 + r;
    int u = s * 64 + wn * 16 + jl;
    cws[i] = c0[n * 512 + u];
  }
  if (i < nacc) facc[i] = 0.f;
}

// ---------------- fused step: LSTM(t) + FC1(t-1) share the staged A tiles ----
// 256 blocks x 512 threads, 1 block/CU. LSTM: 256n x (4g x 64u), K=512+aug32.
// FC1 for t-1 folded into the SAME 8-phase K-loop: phase kt computes FC1
// K-tiles kt (even LDS rows) and kt+8 (odd rows) with B from fc1p (frag-major,
// issued to regs at phase top, hidden under the 64 LSTM MFMAs).
__global__ __launch_bounds__(512, 1) void step256(
    const u16* __restrict__ Wp,     // [2048][512] perm bf16
    const u16* __restrict__ Bxg,    // [2048][32] aug B
    const float* __restrict__ x,    // [8192][20][2] f32
    const u16* __restrict__ hin,    // [8192][512] bf16 = h(t)
    u16* __restrict__ hout,         // h(t+1)
    float* __restrict__ cws,        // c-state, per-thread-linear
    const u16* __restrict__ fc1p,   // frag-major fc1w
    float* __restrict__ facc,       // [4096][512] f32
    int t, int doFacc) {
  extern __shared__ char S[];       // 128 KB: p*65536 + {A:0..32K, B:32K..64K}

  const int tid = threadIdx.x;
  const int lane = tid & 63, wid = tid >> 6;
  const int jl = lane & 15, kg = lane >> 4;
  const int bid = blockIdx.x;
  const int s = (bid >> 3) & 7;
  const int nb = (bid & 7) * 4 + (bid >> 6);
  const int n0 = nb * 256;
  const int srow = tid >> 3;
  const int sw = (tid & 7) ^ (srow & 7);

  const int wm = wid >> 2, wn = wid & 3;        // LSTM wave map 2M x 4N
  const int Fwm = wid >> 1, Fwn = wid & 1;      // FC1 wave map 4M x 2N
  const int u = s * 64 + wn * 16 + jl;
  const int tf = (t > 0) ? (t - 1) : 0;
  const int swz0 = (kg ^ (jl & 7)) * 16;
  const int swz1 = ((4 + kg) ^ (jl & 7)) * 16;
  const int aB0 = wm * 16384 + jl * 128 + swz0;
  const int aB1 = wm * 16384 + jl * 128 + swz1;
  const int bB0 = 32768 + wn * 8192 + jl * 128 + swz0;
  const int bB1 = 32768 + wn * 8192 + jl * 128 + swz1;
  const u16* srcA = hin + (n0 + srow) * 512 + sw * 8;
  const u16* srcB = Wp + (s * 256 + srow) * 512 + sw * 8;
  const u16* fbl = fc1p + (s * 20 + tf) * 65536 + Fwn * 1024 + kg * 128 + jl * 8;

  f32x4 acc[8][4];
#pragma unroll
  for (int mt = 0; mt < 8; ++mt)
#pragma unroll
    for (int f = 0; f < 4; ++f) acc[mt][f] = (f32x4){0.f, 0.f, 0.f, 0.f};
  f32x4 fa[2][2];
#pragma unroll
  for (int a = 0; a < 2; ++a)
#pragma unroll
    for (int b = 0; b < 2; ++b) fa[a][b] = (f32x4){0.f, 0.f, 0.f, 0.f};

  // ---- prologue: x load, Bx stage (->p0 B slot), tile0 stage (->p1) ----
  float2 xv = {0.f, 0.f};
  if (tid < 256) xv = *reinterpret_cast<const float2*>(x + (n0 + tid) * 40 + t * 2);
  {
    const int r0 = tid >> 2, ch = tid & 3;
    gload16(Bxg + (s * 256 + 0 * 128 + r0) * 32 + ch * 8, (u16*)(S + 32768 + 0 * 8192 + wid * 1024));
    gload16(Bxg + (s * 256 + 1 * 128 + r0) * 32 + ch * 8, (u16*)(S + 32768 + 1 * 8192 + wid * 1024));
  }
#pragma unroll
  for (int q = 0; q < 4; ++q) {
    gload16(srcA + q * 32768, (u16*)(S + 65536 + q * 8192 + wid * 1024));
    gload16(srcB + q * 32768, (u16*)(S + 65536 + 32768 + q * 8192 + wid * 1024));
  }
  if (tid < 256) {
    u16 row0[8] = {f2bf(xv.x), f2bf(xv.y), 0x3F80u, 0, 0, 0, 0, 0};
    *reinterpret_cast<uint4*>(S + tid * 64) = *reinterpret_cast<const uint4*>(row0);
    uint4 z = {0u, 0u, 0u, 0u};
    *reinterpret_cast<uint4*>(S + tid * 64 + 16) = z;
    *reinterpret_cast<uint4*>(S + tid * 64 + 32) = z;
    *reinterpret_cast<uint4*>(S + tid * 64 + 48) = z;
  }
  WAITLG();
  WAITV(8);   // Bx (+x) drained; tile0's 8 still in flight
  BAR();
  // ---- aug phase (K=32): gates += x@Wih^T + biases ----
  {
#pragma unroll
    for (int mt = 0; mt < 8; ++mt) {
      bf16x8 a = *reinterpret_cast<const bf16x8*>(S + (wm * 128 + mt * 16 + jl) * 64 + kg * 16);
#pragma unroll
      for (int f = 0; f < 4; ++f) {
        bf16x8 b = *reinterpret_cast<const bf16x8*>(S + 32768 + (wn * 64 + f * 16 + jl) * 64 + kg * 16);
        acc[mt][f] = MFMA16(a, b, acc[mt][f]);
      }
    }
  }
  BAR();

#define LSTAGE(kt, p)                                                              \
  do {                                                                             \
    _Pragma("unroll") for (int q = 0; q < 4; ++q) {                                \
      gload16(srcA + q * 32768 + (kt) * 64, (u16*)(S + (p) * 65536 + q * 8192 + wid * 1024)); \
      gload16(srcB + q * 32768 + (kt) * 64, (u16*)(S + (p) * 65536 + 32768 + q * 8192 + wid * 1024)); \
    }                                                                              \
  } while (0)
#define LCOMP(p)                                                                   \
  do {                                                                             \
    bf16x8 a0[8], b0[4];                                                           \
    _Pragma("unroll") for (int mt = 0; mt < 8; ++mt)                               \
        a0[mt] = *reinterpret_cast<const bf16x8*>(S + (p) * 65536 + aB0 + mt * 2048); \
    _Pragma("unroll") for (int f = 0; f < 4; ++f)                                  \
        b0[f] = *reinterpret_cast<const bf16x8*>(S + (p) * 65536 + bB0 + f * 2048); \
    _Pragma("unroll") for (int mt = 0; mt < 8; ++mt)                               \
      _Pragma("unroll") for (int f = 0; f < 4; ++f)                                \
        acc[mt][f] = MFMA16(a0[mt], b0[f], acc[mt][f]);                            \
    _Pragma("unroll") for (int mt = 0; mt < 8; ++mt)                               \
        a0[mt] = *reinterpret_cast<const bf16x8*>(S + (p) * 65536 + aB1 + mt * 2048); \
    _Pragma("unroll") for (int f = 0; f < 4; ++f)                                  \
        b0[f] = *reinterpret_cast<const bf16x8*>(S + (p) * 65536 + bB1 + f * 2048); \
    _Pragma("unroll") for (int mt = 0; mt < 8; ++mt)                               \
      _Pragma("unroll") for (int f = 0; f < 4; ++f)                                \
        acc[mt][f] = MFMA16(a0[mt], b0[f], acc[mt][f]);                            \
  } while (0)

#pragma unroll
  for (int kt = 0; kt < 8; ++kt) {
    // FC1 B frags for this phase (regs; latency hidden under the LSTM MFMAs —
    // compiler emits its own counted vmcnt before first use, leaving the
    // tile-(kt+1) stage in flight)
    bf16x8 fbe[2][2], fbo[2][2];
#pragma unroll
    for (int jf = 0; jf < 2; ++jf)
#pragma unroll
      for (int kk = 0; kk < 2; ++kk) {
        fbe[jf][kk] = *reinterpret_cast<const bf16x8*>(fbl + (2 * kt + kk) * 2048 + jf * 512);
        fbo[jf][kk] = *reinterpret_cast<const bf16x8*>(fbl + (2 * kt + 16 + kk) * 2048 + jf * 512);
      }
    if (kt < 7) {
      if ((kt + 1) & 1) LSTAGE(kt + 1, 0); else LSTAGE(kt + 1, 1);
      WAITV(16);   // drains tile kt (oldest 8); tile kt+1 + fb stay in flight
    } else {
      WAITV(8);    // drains tile 7; fb(7) stays in flight
    }
    BAR();
    __builtin_amdgcn_s_setprio(1);
    if (kt & 1) LCOMP(0); else LCOMP(1);
    __builtin_amdgcn_s_setprio(0);
    // ---- FC1 tiles kt (even rows) and kt+8 (odd rows) from the same A buffer
    {
      const int P = (kt & 1) ? 0 : 1;
#pragma unroll
      for (int kk = 0; kk < 2; ++kk) {
#pragma unroll
        for (int mf = 0; mf < 2; ++mf) {
          const int er = Fwm * 64 + mf * 32 + 2 * jl;
          bf16x8 ae = *reinterpret_cast<const bf16x8*>(
              S + P * 65536 + er * 128 + (((kk * 4) + kg) ^ (er & 7)) * 16);
          bf16x8 ao = *reinterpret_cast<const bf16x8*>(
              S + P * 65536 + (er + 1) * 128 + (((kk * 4) + kg) ^ ((er + 1) & 7)) * 16);
#pragma unroll
          for (int jf = 0; jf < 2; ++jf) {
            fa[mf][jf] = MFMA16(ae, fbe[jf][kk], fa[mf][jf]);
            fa[mf][jf] = MFMA16(ao, fbo[jf][kk], fa[mf][jf]);
          }
        }
      }
    }
    BAR();
  }

  // ---- LSTM activation epilogue: c in per-thread-linear layout ----
  float* cbase = cws + ((bid * 8 + wid) * 64 + lane) * 32;
#pragma unroll
  for (int mt = 0; mt < 8; ++mt) {
    f32x4 cv = *reinterpret_cast<f32x4*>(cbase + mt * 4);
    f32x4 cn;
    float hn[4];
#pragma unroll
    for (int r = 0; r < 4; ++r) {
      float iv = sig_(acc[mt][0][r]);
      float fv = sig_(acc[mt][1][r]);
      float gv = tanh_(acc[mt][2][r]);
      float ov = sig_(acc[mt][3][r]);
      float c2 = fv * cv[r] + iv * gv;
      cn[r] = c2;
      hn[r] = ov * tanh_(c2);
    }
    *reinterpret_cast<f32x4*>(cbase + mt * 4) = cn;
#pragma unroll
    for (int r = 0; r < 4; ++r)
      hout[(n0 + wm * 128 + mt * 16 + kg * 4 + r) * 512 + u] = f2bf(hn[r]);
  }

  // ---- FC1 accumulate to global (skip at t=0: fa holds garbage-free tf=0 dup,
  //      but doFacc=0 discards it) ----
  if (doFacc) {
    const int Fm0 = nb * 128, Fj0 = s * 64;
#pragma unroll
    for (int mf = 0; mf < 2; ++mf)
#pragma unroll
      for (int jf = 0; jf < 2; ++jf) {
        int j = Fj0 + Fwn * 32 + jf * 16 + jl;
#pragma unroll
        for (int r = 0; r < 4; ++r) {
          int m = Fm0 + Fwm * 32 + mf * 16 + kg * 4 + r;
          facc[m * 512 + j] += fa[mf][jf][r];
        }
      }
  }
}

// ---------------- tail: FC1 for t=19 (A = h(20)), same fused scheme ----------
__global__ __launch_bounds__(512, 1) void fc1_tail(
    const u16* __restrict__ hin, const u16* __restrict__ fc1p,
    float* __restrict__ facc) {
  extern __shared__ char S[];
  const int tid = threadIdx.x;
  const int lane = tid & 63, wid = tid >> 6;
  const int jl = lane & 15, kg = lane >> 4;
  const int bid = blockIdx.x;
  const int s = (bid >> 3) & 7;
  const int nb = (bid & 7) * 4 + (bid >> 6);
  const int n0 = nb * 256;
  const int srow = tid >> 3;
  const int sw = (tid & 7) ^ (srow & 7);
  const int Fwm = wid >> 1, Fwn = wid & 1;
  const u16* srcA = hin + (n0 + srow) * 512 + sw * 8;
  const u16* fbl = fc1p + (s * 20 + 19) * 65536 + Fwn * 1024 + kg * 128 + jl * 8;

  f32x4 fa[2][2];
#pragma unroll
  for (int a = 0; a < 2; ++a)
#pragma unroll
    for (int b = 0; b < 2; ++b) fa[a][b] = (f32x4){0.f, 0.f, 0.f, 0.f};

  // prologue: stage tile0 A -> p1
#pragma unroll
  for (int q = 0; q < 4; ++q)
    gload16(srcA + q * 32768, (u16*)(S + 65536 + q * 8192 + wid * 1024));

#pragma unroll
  for (int kt = 0; kt < 8; ++kt) {
    bf16x8 fbe[2][2], fbo[2][2];
#pragma unroll
    for (int jf = 0; jf < 2; ++jf)
#pragma unroll
      for (int kk = 0; kk < 2; ++kk) {
        fbe[jf][kk] = *reinterpret_cast<const bf16x8*>(fbl + (2 * kt + kk) * 2048 + jf * 512);
        fbo[jf][kk] = *reinterpret_cast<const bf16x8*>(fbl + (2 * kt + 16 + kk) * 2048 + jf * 512);
      }
    if (kt < 7) {
      const int pn = ((kt + 1) & 1) ? 0 : 1;
#pragma unroll
      for (int q = 0; q < 4; ++q)
        gload16(srcA + q * 32768 + (kt + 1) * 64, (u16*)(S + pn * 65536 + q * 8192 + wid * 1024));
      WAITV(12);  // drains tile kt (4 oldest); fb + tile kt+1 in flight
    } else {
      WAITV(8);
    }
    BAR();
    {
      const int P = (kt & 1) ? 0 : 1;
#pragma unroll
      for (int kk = 0; kk < 2; ++kk) {
#pragma unroll
        for (int mf = 0; mf < 2; ++mf) {
          const int er = Fwm * 64 + mf * 32 + 2 * jl;
          bf16x8 ae = *reinterpret_cast<const bf16x8*>(
              S + P * 65536 + er * 128 + (((kk * 4) + kg) ^ (er & 7)) * 16);
          bf16x8 ao = *reinterpret_cast<const bf16x8*>(
              S + P * 65536 + (er + 1) * 128 + (((kk * 4) + kg) ^ ((er + 1) & 7)) * 16);
#pragma unroll
          for (int jf = 0; jf < 2; ++jf) {
            fa[mf][jf] = MFMA16(ae, fbe[jf][kk], fa[mf][jf]);
            fa[mf][jf] = MFMA16(ao, fbo[jf][kk], fa[mf][jf]);
          }
        }
      }
    }
    BAR();
  }

  const int Fm0 = nb * 128, Fj0 = s * 64;
#pragma unroll
  for (int mf = 0; mf < 2; ++mf)
#pragma unroll
    for (int jf = 0; jf < 2; ++jf) {
      int j = Fj0 + Fwn * 32 + jf * 16 + jl;
#pragma unroll
      for (int r = 0; r < 4; ++r) {
        int m = Fm0 + Fwm * 32 + mf * 16 + kg * 4 + r;
        facc[m * 512 + j] += fa[mf][jf][r];
      }
    }
}

// ---------------- head: relu(facc + b1) @ fc2^T + b2, sigmoid ----------------
__global__ __launch_bounds__(256) void head_kernel(
    const float* __restrict__ acc, const float* __restrict__ fc1b,
    const float* __restrict__ fc2w, const float* __restrict__ fc2b,
    float* __restrict__ out) {
  int lane = threadIdx.x & 63;
  int row = blockIdx.x * 4 + (threadIdx.x >> 6);
  float sum = 0.f;
#pragma unroll
  for (int j = lane; j < 512; j += 64)
    sum += fmaxf(acc[row * 512 + j] + fc1b[j], 0.f) * fc2w[j];
#pragma unroll
  for (int off = 32; off; off >>= 1) sum += __shfl_down(sum, off);
  if (lane == 0) out[row] = sig_(sum + fc2b[0]);
}

extern "C" void kernel_launch(void* const* d_in, const int* in_sizes, int n_in,
                              void* d_out, int out_size, void* d_ws, size_t ws_size,
                              hipStream_t stream) {
  const float* x = (const float*)d_in[0];
  const float* h0 = (const float*)d_in[2];
  const float* c0 = (const float*)d_in[3];
  const float* Wih = (const float*)d_in[4];
  const float* Whh = (const float*)d_in[5];
  const float* bih = (const float*)d_in[6];
  const float* bhh = (const float*)d_in[7];
  const float* fc1w = (const float*)d_in[8];
  const float* fc1b = (const float*)d_in[9];
  const float* fc2w = (const float*)d_in[10];
  const float* fc2b = (const float*)d_in[11];
  float* out = (float*)d_out;

  char* ws = (char*)d_ws;
  const size_t MB = 1 << 20;
  u16* Wp = (u16*)(ws);                  //  2 MB perm Whh
  u16* fc1p = (u16*)(ws + 2 * MB);       // 20 MB frag-major fc1w
  u16* hbf0 = (u16*)(ws + 22 * MB);      //  8 MB
  u16* hbf1 = (u16*)(ws + 30 * MB);      //  8 MB
  float* cws = (float*)(ws + 38 * MB);   // 16 MB (per-thread-linear c)
  float* facc = (float*)(ws + 54 * MB);  //  8 MB
  u16* Bxg = (u16*)(ws + 62 * MB);       // 128 KB

  (void)hipFuncSetAttribute(reinterpret_cast<const void*>(step256),
                            hipFuncAttributeMaxDynamicSharedMemorySize, SMEM_BYTES);
  (void)hipFuncSetAttribute(reinterpret_cast<const void*>(fc1_tail),
                            hipFuncAttributeMaxDynamicSharedMemorySize, SMEM_BYTES);

  convert_whh_p<<<2048, 512, 0, stream>>>(Whh, Wp);
  bx_prep<<<8, 256, 0, stream>>>(Wih, bih, bhh, Bxg);
  fc1p_prep<<<2560, 512, 0, stream>>>(fc1w, fc1p);
  init_state<<<16384, 256, 0, stream>>>(h0, c0, hbf0, cws, facc, 8192 * 512, 4096 * 512);

  u16* hb[2] = {hbf0, hbf1};
  for (int t = 0; t < TSTEPS; ++t) {
    step256<<<256, 512, SMEM_BYTES, stream>>>(
        Wp, Bxg, x, hb[t & 1], hb[(t + 1) & 1], cws, fc1p, facc, t, t > 0 ? 1 : 0);
  }
  fc1_tail<<<256, 512, SMEM_BYTES, stream>>>(hb[0], fc1p, facc);
  head_kernel<<<1024, 256, 0, stream>>>(facc, fc1b, fc2w, fc2b, out);
}